// Round 1
// 395.804 us; speedup vs baseline: 1.0675x; 1.0675x over previous
//
#include <hip/hip_runtime.h>

// LSTM_61203283968689 — R7: input-half/self-half MFMA split with one-tick
// deferral so each wave carries independent MFMA work into its own ew phase.
// Diagonal deepened: L0 step t @ tick t, L1 step s @ s+2, L2 step s @ s+4
// (516 ticks). Per tick per wave: [barrier] read self frags -> 8 self-MFMA
// (accumulate onto carried zc) -> ew (10 trans) overlapped with 8 input-MFMA
// for the NEXT step (into fresh zc) -> [barrier]. The input MFMAs are
// independent of the ew chain and live in the same basic block, so the
// scheduler fills trans-chain stalls with matrix-pipe work (R6 serialized
// these phases: 906cy MFMA + 480cy trans + 250cy VALU ~= 1718cy/tick).
// Steady-state loop is branch-free via edge/steady template instantiation.
// Accumulation order per gate unchanged: bias, ih-lo, ih-hi, hh-lo, hh-hi.
// Everything else (layout, staging, 82 KiB LDS -> 1 block/CU) as R6.

#define TT   512
#define NTH  768
#define NBLK 256

typedef _Float16 h16;
typedef __attribute__((ext_vector_type(8))) _Float16 h16x8;
typedef __attribute__((ext_vector_type(4))) float f32x4;

#define MFMA16(a, b, c) __builtin_amdgcn_mfma_f32_16x16x32_f16((a), (b), (c), 0, 0, 0)

__device__ __forceinline__ float sigm(float z) {
    return __builtin_amdgcn_rcpf(1.f + __expf(-z));
}

// B-fragment: 8 consecutive k of row `ro` from row-major W[.,ld], f32 -> f16.
__device__ __forceinline__ h16x8 loadB(const float* __restrict__ W, int ld, int ro,
                                       int k0, int kmax) {
    h16x8 r;
    #pragma unroll
    for (int i = 0; i < 8; ++i) {
        const int k = k0 + i;
        r[i] = (h16)((k < kmax) ? W[(size_t)ro * ld + k] : 0.f);
    }
    return r;
}

struct TrueC  { static constexpr bool value = true;  };
struct FalseC { static constexpr bool value = false; };

__global__ __attribute__((amdgpu_flat_work_group_size(NTH, NTH), amdgpu_waves_per_eu(3)))
void lstm_mfma(
    const float* __restrict__ x,
    const float* __restrict__ wih0, const float* __restrict__ whh0,
    const float* __restrict__ bih0, const float* __restrict__ bhh0,
    const float* __restrict__ wih1, const float* __restrict__ whh1,
    const float* __restrict__ bih1, const float* __restrict__ bhh1,
    const float* __restrict__ wih2, const float* __restrict__ whh2,
    const float* __restrict__ bih2, const float* __restrict__ bhh2,
    const float* __restrict__ wfc, const float* __restrict__ bfc,
    float* __restrict__ out)
{
    const int tid  = threadIdx.x;
    const int w    = tid >> 6;        // wave 0..11
    const int wl   = w >> 2;          // layer 0..2
    const int wg   = w & 3;           // gate-tile group: units [16wg, 16wg+16)
    const int lane = tid & 63;
    const int nloc = lane & 15;       // unit-local index / B-frag col
    const int kg   = lane >> 4;       // k-group 0..3 ; also sample (C-row 4*kg)
    const int b4   = blockIdx.x * 4;
    const int u    = wg * 16 + nloc;  // this lane's hidden unit

    // LDS: XL 64 KiB + HT 12 KiB + PAD 6 KiB = 82 KiB -> exactly 1 block/CU
    __shared__ alignas(16) h16 XL[2 * 32 * 512];   // x, 2 chunks x 32 t x frag-tile(512)
    __shared__ alignas(16) h16 HT[3 * 2 * 1024];   // h[layer][pp] frag-tiles
    __shared__ h16 PAD[3072];                      // occupancy limiter (kept alive below)

    // ---------------- B fragments for THIS wave's layer only ----------------
    h16x8 Bf[4][4];
    float bias[4];
    #pragma unroll
    for (int g = 0; g < 4; ++g) {
        const int ro = g * 64 + u;                  // original row (i,f,g,o blocks)
        if (wl == 0) {
            Bf[g][0] = loadB(wih0, 22, ro, kg * 8,      22);
            Bf[g][1] = loadB(whh0, 64, ro, kg * 8,      64);
            Bf[g][2] = loadB(whh0, 64, ro, 32 + kg * 8, 64);
            Bf[g][3] = Bf[g][2];
            bias[g]  = bih0[ro] + bhh0[ro];
        } else if (wl == 1) {
            Bf[g][0] = loadB(wih1, 64, ro, kg * 8,      64);
            Bf[g][1] = loadB(wih1, 64, ro, 32 + kg * 8, 64);
            Bf[g][2] = loadB(whh1, 64, ro, kg * 8,      64);
            Bf[g][3] = loadB(whh1, 64, ro, 32 + kg * 8, 64);
            bias[g]  = bih1[ro] + bhh1[ro];
        } else {
            Bf[g][0] = loadB(wih2, 64, ro, kg * 8,      64);
            Bf[g][1] = loadB(wih2, 64, ro, 32 + kg * 8, 64);
            Bf[g][2] = loadB(whh2, 64, ro, kg * 8,      64);
            Bf[g][3] = loadB(whh2, 64, ro, 32 + kg * 8, 64);
            bias[g]  = bih2[ro] + bhh2[ro];
        }
    }

    // keep PAD alive (condition can never be true at runtime)
    if (bias[0] > 1.0e30f) { PAD[tid & 2047] = (h16)bias[0]; out[0] = (float)PAD[0]; }

    // ---------------- zero LDS (pad rows must stay zero) ----------------
    {
        int* xz = (int*)XL;
        for (int i = tid; i < 2 * 32 * 256; i += NTH) xz[i] = 0;
        int* hz = (int*)HT;
        for (int i = tid; i < 3 * 2 * 512; i += NTH) hz[i] = 0;
    }
    __syncthreads();

    // ---------------- x staging: sample bl -> A-row 4*bl, frag layout ------------
    auto stage_x = [&](int chunk) {
        if (tid < 4 * 22) {
            const int bl = tid / 22, ii = tid - bl * 22;
            const float* src = x + (size_t)(b4 + bl) * (22 * 512) + (size_t)ii * 512
                                 + chunk * 32;
            h16* dst = &XL[(chunk & 1) * (32 * 512) + (ii >> 3) * 128 + (4 * bl) * 8 + (ii & 7)];
            #pragma unroll
            for (int q = 0; q < 8; ++q) {
                const float4 v = ((const float4*)src)[q];
                dst[(q * 4 + 0) * 512] = (h16)v.x;
                dst[(q * 4 + 1) * 512] = (h16)v.y;
                dst[(q * 4 + 2) * 512] = (h16)v.z;
                dst[(q * 4 + 3) * 512] = (h16)v.w;
            }
        }
    };
    stage_x(0);

    // ---------------- per-lane constants ----------------
    const int lo8  = lane * 8;                           // A-frag offset (h16 units)
    const int hoff = (u >> 3) * 128 + kg * 32 + (u & 7); // h-write: row 4*kg, unit u

    float cst = 0.f;

    auto ew = [&](const f32x4& zi, const f32x4& zf, const f32x4& zg, const f32x4& zo,
                  h16* hb) {
        const float vi = sigm(zi[0]);
        const float vf = sigm(zf[0]);
        const float vg = 2.f * sigm(2.f * zg[0]) - 1.f;
        const float vo = sigm(zo[0]);
        const float c  = vf * cst + vi * vg;
        cst = c;
        hb[hoff] = (h16)(vo * (2.f * sigm(2.f * c) - 1.f));
    };

    // gate-bias C fragments (read-only; MFMA C-in by value, so zero movs/tick)
    f32x4 zb[4];
    #pragma unroll
    for (int g = 0; g < 4; ++g) zb[g] = f32x4{bias[g], 0.f, 0.f, 0.f};

    __syncthreads();

    // ---- prologue: zc carries bias + input-half contribution of the NEXT step ----
    f32x4 zc[4];
    if (wl == 0) {
        const h16x8 ax0 = *(const h16x8*)&XL[lo8];   // chunk 0, t=0
        #pragma unroll
        for (int g = 0; g < 4; ++g) zc[g] = MFMA16(ax0, Bf[g][0], zb[g]);
    } else {
        #pragma unroll
        for (int g = 0; g < 4; ++g) zc[g] = zb[g];
    }

    // ============================ diagonal tick loop ============================
    auto tick = [&](int t, auto edgec) {
        constexpr bool EDGE = decltype(edgec)::value;
        const int wb = t & 1, rb = wb ^ 1;
        const h16* h0r = HT + 0 * 2048 + rb * 1024;
        h16*       h0w = HT + 0 * 2048 + wb * 1024;
        const h16* h1r = HT + 1 * 2048 + rb * 1024;
        h16*       h1w = HT + 1 * 2048 + wb * 1024;
        const h16* h2r = HT + 2 * 2048 + rb * 1024;
        h16*       h2w = HT + 2 * 2048 + wb * 1024;

        if (wl == 0) {           // -------- L0: self for step t, x-prefetch t+1 ------
            const bool sa = !EDGE || (t < TT);
            const bool ia = !EDGE || (t < TT - 1);
            f32x4 z[4];
            h16x8 a0lo, a0hi, axn;
            if (sa) {
                a0lo = *(const h16x8*)(h0r + lo8);
                a0hi = *(const h16x8*)(h0r + lo8 + 512);
            }
            if (ia) {
                const int tn = t + 1;
                axn = *(const h16x8*)&XL[((tn >> 5) & 1) * (32 * 512) + (tn & 31) * 512 + lo8];
            }
            if (sa) {
                #pragma unroll
                for (int g = 0; g < 4; ++g) {
                    z[g] = MFMA16(a0lo, Bf[g][1], zc[g]);
                    z[g] = MFMA16(a0hi, Bf[g][2], z[g]);
                }
            }
            if ((t & 31) == 16 && (t >> 5) < 15) stage_x((t >> 5) + 1);
            if (sa) ew(z[0], z[1], z[2], z[3], h0w);
            if (ia) {
                #pragma unroll
                for (int g = 0; g < 4; ++g)
                    zc[g] = MFMA16(axn, Bf[g][0], zb[g]);
            }
        } else if (wl == 1) {    // ---- L1: self for step t-2, input-prefetch t-1 ----
            const bool sa = !EDGE || (t >= 2 && t < TT + 2);
            const bool ia = !EDGE || (t >= 1 && t < TT + 1);
            f32x4 z[4];
            h16x8 a1lo, a1hi, a0lo, a0hi;
            if (sa) {
                a1lo = *(const h16x8*)(h1r + lo8);
                a1hi = *(const h16x8*)(h1r + lo8 + 512);
            }
            if (ia) {
                a0lo = *(const h16x8*)(h0r + lo8);
                a0hi = *(const h16x8*)(h0r + lo8 + 512);
            }
            if (sa) {
                #pragma unroll
                for (int g = 0; g < 4; ++g) {
                    z[g] = MFMA16(a1lo, Bf[g][2], zc[g]);
                    z[g] = MFMA16(a1hi, Bf[g][3], z[g]);
                }
            }
            if (sa) ew(z[0], z[1], z[2], z[3], h1w);
            if (ia) {
                #pragma unroll
                for (int g = 0; g < 4; ++g) {
                    f32x4 zn = MFMA16(a0lo, Bf[g][0], zb[g]);
                    zc[g] = MFMA16(a0hi, Bf[g][1], zn);
                }
            }
        } else {                 // ---- L2: self for step t-4, input-prefetch t-3 ----
            const bool sa = !EDGE || (t >= 4);
            const bool ia = !EDGE || (t >= 3 && t < TT + 3);
            f32x4 z[4];
            h16x8 a2lo, a2hi, a1lo, a1hi;
            if (sa) {
                a2lo = *(const h16x8*)(h2r + lo8);
                a2hi = *(const h16x8*)(h2r + lo8 + 512);
            }
            if (ia) {
                a1lo = *(const h16x8*)(h1r + lo8);
                a1hi = *(const h16x8*)(h1r + lo8 + 512);
            }
            if (sa) {
                #pragma unroll
                for (int g = 0; g < 4; ++g) {
                    z[g] = MFMA16(a2lo, Bf[g][2], zc[g]);
                    z[g] = MFMA16(a2hi, Bf[g][3], z[g]);
                }
            }
            if (sa) ew(z[0], z[1], z[2], z[3], h2w);
            if (ia) {
                #pragma unroll
                for (int g = 0; g < 4; ++g) {
                    f32x4 zn = MFMA16(a1lo, Bf[g][0], zb[g]);
                    zc[g] = MFMA16(a1hi, Bf[g][1], zn);
                }
            }
        }
        __syncthreads();
    };

    #pragma unroll 1
    for (int t = 0; t < 4; ++t) tick(t, TrueC{});
    #pragma unroll 1
    for (int t = 4; t < TT - 1; ++t) tick(t, FalseC{});     // branch-free steady state
    #pragma unroll 1
    for (int t = TT - 1; t < TT + 4; ++t) tick(t, TrueC{});

    // ------------- FC epilogue: h2(step 511) written at tick 515 -> buffer 1 ------
    if (tid < 16) {
        const int ms = tid >> 2, o = tid & 3;
        const h16* h2 = HT + 2 * 2048 + 1024;
        float acc = bfc[o];
        #pragma unroll 1
        for (int uu = 0; uu < 64; ++uu)
            acc += (float)h2[(uu >> 3) * 128 + (4 * ms) * 8 + (uu & 7)] * wfc[o * 64 + uu];
        out[(b4 + ms) * 4 + o] = acc;
    }
}

extern "C" void kernel_launch(void* const* d_in, const int* in_sizes, int n_in,
                              void* d_out, int out_size, void* d_ws, size_t ws_size,
                              hipStream_t stream) {
    const float* x    = (const float*)d_in[0];
    const float* wih0 = (const float*)d_in[1];
    const float* whh0 = (const float*)d_in[2];
    const float* bih0 = (const float*)d_in[3];
    const float* bhh0 = (const float*)d_in[4];
    const float* wih1 = (const float*)d_in[5];
    const float* whh1 = (const float*)d_in[6];
    const float* bih1 = (const float*)d_in[7];
    const float* bhh1 = (const float*)d_in[8];
    const float* wih2 = (const float*)d_in[9];
    const float* whh2 = (const float*)d_in[10];
    const float* bih2 = (const float*)d_in[11];
    const float* bhh2 = (const float*)d_in[12];
    const float* wfc  = (const float*)d_in[13];
    const float* bfc  = (const float*)d_in[14];
    float* out = (float*)d_out;

    lstm_mfma<<<dim3(NBLK), dim3(NTH), 0, stream>>>(
        x, wih0, whh0, bih0, bhh0, wih1, whh1, bih1, bhh1,
        wih2, whh2, bih2, bhh2, wfc, bfc, out);
}